// Round 1
// baseline (322.046 us; speedup 1.0000x reference)
//
#include <hip/hip_runtime.h>
#include <hip/hip_bf16.h>

#define NH 16
#define HD 64
#define CE 1024
#define TT 2048
#define BB 2
#define MR (BB*TT)   // 4096 rows

typedef __attribute__((ext_vector_type(4))) float f32x4;
typedef __attribute__((ext_vector_type(8))) short s16x8;

__device__ __forceinline__ unsigned short f2b(float f) {
  union { __hip_bfloat16 b; unsigned short u; } t;
  t.b = __float2bfloat16(f);
  return t.u;
}
__device__ __forceinline__ float red64_sum(float v) {
#pragma unroll
  for (int m = 1; m < 64; m <<= 1) v += __shfl_xor(v, m, 64);
  return v;
}
__device__ __forceinline__ float red16_sum(float v) {
#pragma unroll
  for (int m = 1; m < 16; m <<= 1) v += __shfl_xor(v, m, 64);
  return v;
}
__device__ __forceinline__ float red16_max(float v) {
#pragma unroll
  for (int m = 1; m < 16; m <<= 1) v = fmaxf(v, __shfl_xor(v, m, 64));
  return v;
}
__device__ __forceinline__ float softplusf(float x) {
  return x > 20.0f ? x : log1pf(expf(x));
}

// ---------------- x -> bf16 ----------------
__global__ __launch_bounds__(256) void cvt_x(const float* __restrict__ x,
                                             unsigned short* __restrict__ xb, int n4) {
  int stride = gridDim.x * blockDim.x;
  for (int i = blockIdx.x * blockDim.x + threadIdx.x; i < n4; i += stride) {
    float4 v = ((const float4*)x)[i];
    union { unsigned short u[4]; uint2 p; } o;
    o.u[0] = f2b(v.x); o.u[1] = f2b(v.y); o.u[2] = f2b(v.z); o.u[3] = f2b(v.w);
    ((uint2*)xb)[i] = o.p;
  }
}

// ------- W [K][N] fp32 -> Wt [N][K] bf16 (transposed so B-frags are k-contiguous) -------
__global__ __launch_bounds__(256) void cvt_wt(const float* __restrict__ W0, const float* __restrict__ W1,
                                              const float* __restrict__ W2, const float* __restrict__ W3,
                                              unsigned short* __restrict__ T0, unsigned short* __restrict__ T1,
                                              unsigned short* __restrict__ T2, unsigned short* __restrict__ T3) {
  const float* W = blockIdx.z == 0 ? W0 : blockIdx.z == 1 ? W1 : blockIdx.z == 2 ? W2 : W3;
  unsigned short* T = blockIdx.z == 0 ? T0 : blockIdx.z == 1 ? T1 : blockIdx.z == 2 ? T2 : T3;
  __shared__ float t[64][65];
  int k0 = blockIdx.x * 64, n0 = blockIdx.y * 64;
  int row = threadIdx.x >> 2, seg = threadIdx.x & 3;
#pragma unroll
  for (int i = 0; i < 4; ++i) {
    float4 v = *(const float4*)(W + (size_t)(k0 + row) * CE + n0 + seg * 16 + i * 4);
    int c = seg * 16 + i * 4;
    t[row][c + 0] = v.x; t[row][c + 1] = v.y; t[row][c + 2] = v.z; t[row][c + 3] = v.w;
  }
  __syncthreads();
#pragma unroll
  for (int it = 0; it < 2; ++it) {
    int c = threadIdx.x + it * 256;
    int n = c >> 3, ks = (c & 7) * 8;
    union { unsigned short u[8]; uint4 p; } o;
#pragma unroll
    for (int e = 0; e < 8; ++e) o.u[e] = f2b(t[ks + e][n]);
    *(uint4*)(T + (size_t)(n0 + n) * CE + k0 + ks) = o.p;
  }
}

// ---------------- bf16 GEMM: C[M,N] = A[M,K] @ Bt[N,K]^T, fp32 C ----------------
#define BM 128
#define BN 128
#define BK 64
__global__ __launch_bounds__(256) void gemm3(const unsigned short* __restrict__ A,
    const unsigned short* __restrict__ B0, const unsigned short* __restrict__ B1,
    const unsigned short* __restrict__ B2,
    float* __restrict__ C0, float* __restrict__ C1, float* __restrict__ C2,
    int M, int N, int K) {
  const unsigned short* Bt = blockIdx.z == 0 ? B0 : blockIdx.z == 1 ? B1 : B2;
  float* C = blockIdx.z == 0 ? C0 : blockIdx.z == 1 ? C1 : C2;
  __shared__ __align__(16) unsigned short aT[BM * BK];  // [128][64] xor-swizzled 16B slots
  __shared__ __align__(16) unsigned short bT[BN * BK];
  int tid = threadIdx.x;
  int w = tid >> 6, lane = tid & 63, q4 = lane >> 4, r16 = lane & 15;
  int m0 = blockIdx.y * BM, n0 = blockIdx.x * BN;
  int wm = (w >> 1) * 64, wn = (w & 1) * 64;
  f32x4 acc[4][4] = {};
  for (int k0 = 0; k0 < K; k0 += BK) {
#pragma unroll
    for (int it = 0; it < 4; ++it) {
      int c = tid + it * 256;
      int row = c >> 3, sl = c & 7;
      s16x8 va = *(const s16x8*)(A + (size_t)(m0 + row) * K + k0 + sl * 8);
      *(s16x8*)((char*)aT + row * 128 + ((sl ^ (row & 7)) << 4)) = va;
      s16x8 vb = *(const s16x8*)(Bt + (size_t)(n0 + row) * K + k0 + sl * 8);
      *(s16x8*)((char*)bT + row * 128 + ((sl ^ (row & 7)) << 4)) = vb;
    }
    __syncthreads();
#pragma unroll
    for (int kk = 0; kk < 2; ++kk) {
      s16x8 af[4], bfr[4];
#pragma unroll
      for (int i = 0; i < 4; ++i) {
        int ra = wm + i * 16 + r16;
        af[i] = *(const s16x8*)((char*)aT + ra * 128 + ((((kk << 2) | q4) ^ (ra & 7)) << 4));
        int rb = wn + i * 16 + r16;
        bfr[i] = *(const s16x8*)((char*)bT + rb * 128 + ((((kk << 2) | q4) ^ (rb & 7)) << 4));
      }
#pragma unroll
      for (int i = 0; i < 4; ++i)
#pragma unroll
        for (int j = 0; j < 4; ++j)
          acc[i][j] = __builtin_amdgcn_mfma_f32_16x16x32_bf16(af[i], bfr[j], acc[i][j], 0, 0, 0);
    }
    __syncthreads();
  }
#pragma unroll
  for (int i = 0; i < 4; ++i)
#pragma unroll
    for (int j = 0; j < 4; ++j)
#pragma unroll
      for (int r = 0; r < 4; ++r) {
        int gm = m0 + wm + i * 16 + (q4 << 2) + r;
        int gn = n0 + wn + j * 16 + r16;
        C[(size_t)gm * N + gn] = acc[i][j][r];
      }
}

// ---- RMSNorm(q,k) + gate, pack q/k to [B,H,T,D] bf16 (1/8 folded into q), v -> [B,H,D,T] bf16 ----
__global__ __launch_bounds__(256) void rmsgate(const float* __restrict__ q, const float* __restrict__ k,
    const float* __restrict__ v, const float* __restrict__ qw, const float* __restrict__ kw,
    const float* __restrict__ omega, const float* __restrict__ u,
    unsigned short* __restrict__ qb, unsigned short* __restrict__ kb,
    unsigned short* __restrict__ vtb, float* __restrict__ cg) {
  int b = blockIdx.z, h = blockIdx.y, t0 = blockIdx.x * 64;
  int tid = threadIdx.x, w = tid >> 6, lane = tid & 63;
  float uv = u[h * HD + lane];
  float us = red64_sum(uv * uv);
  float un = uv / fmaxf(sqrtf(us), 1e-6f);
  float qwl = qw[lane], kwl = kw[lane];
  float weff = softplusf(omega[h]) * exp2f(-0.5f * (float)(h + 1));  // softplus(w)*slope_h
  size_t hb = ((size_t)(b * NH + h)) * TT;
#pragma unroll 4
  for (int it = 0; it < 16; ++it) {
    int t = t0 + w * 16 + it;
    size_t roff = ((size_t)(b * TT + t)) * CE + h * HD + lane;
    float qv = q[roff];
    float rq = rsqrtf(red64_sum(qv * qv) * (1.0f / 64.0f) + 1e-5f);
    qb[(hb + t) * HD + lane] = f2b(qv * rq * qwl * 0.125f);
    float kv = k[roff];
    float rk = rsqrtf(red64_sum(kv * kv) * (1.0f / 64.0f) + 1e-5f);
    float kn = kv * rk * kwl;
    kb[(hb + t) * HD + lane] = f2b(kn);
    float gl = red64_sum(kn * un) * 0.125f;   // (k̂·û)/sqrt(D), fp32 path
    if (lane == 0) cg[hb + t] = weff * softplusf(gl);
  }
  // v transpose via padded LDS tile (pitch 65 breaks bank alignment)
  __shared__ unsigned short vt[64 * 65];
  int row = tid >> 2, seg = tid & 3;
#pragma unroll
  for (int i = 0; i < 4; ++i) {
    float4 vv = *(const float4*)(v + ((size_t)(b * TT + t0 + row)) * CE + h * HD + seg * 16 + i * 4);
    int d = seg * 16 + i * 4;
    vt[(d + 0) * 65 + row] = f2b(vv.x);
    vt[(d + 1) * 65 + row] = f2b(vv.y);
    vt[(d + 2) * 65 + row] = f2b(vv.z);
    vt[(d + 3) * 65 + row] = f2b(vv.w);
  }
  __syncthreads();
#pragma unroll
  for (int it = 0; it < 2; ++it) {
    int c = tid + it * 256;
    int d = c >> 3, js = (c & 7) * 8;
    union { unsigned short u[8]; uint4 p; } o;
#pragma unroll
    for (int e = 0; e < 8; ++e) o.u[e] = vt[d * 65 + js + e];
    *(uint4*)(vtb + (((size_t)(b * NH + h)) * HD + d) * TT + t0 + js) = o.p;
  }
}

// ---------------- causal flash attention with key-gated ALiBi bias ----------------
#define QB 64
#define KVB 64
__global__ __launch_bounds__(256) void attn(const unsigned short* __restrict__ qb,
    const unsigned short* __restrict__ kb, const unsigned short* __restrict__ vtb,
    const float* __restrict__ cg, unsigned short* __restrict__ y) {
  int b = blockIdx.z, h = blockIdx.y, qt = blockIdx.x * QB;
  int tid = threadIdx.x, w = tid >> 6, lane = tid & 63, q4 = lane >> 4, r16 = lane & 15;
  __shared__ __align__(16) unsigned short kl[KVB * 64];   // [j][d] swizzled
  __shared__ __align__(16) unsigned short vl[64 * KVB];   // [d][j] swizzled
  __shared__ float cgl[KVB];
  __shared__ __align__(16) unsigned short pl[4][16 * 64]; // per-wave P, [i][j] swizzled
  size_t hb = ((size_t)(b * NH + h)) * TT;
  int qrow = qt + w * 16 + r16;
  s16x8 qf[2];
  qf[0] = *(const s16x8*)(qb + (hb + qrow) * HD + q4 * 8);
  qf[1] = *(const s16x8*)(qb + (hb + qrow) * HD + 32 + q4 * 8);
  f32x4 acc[4] = {};
  float mr[4] = {-1e30f, -1e30f, -1e30f, -1e30f};
  float lr[4] = {0.f, 0.f, 0.f, 0.f};
  int i_base = qt + w * 16 + (q4 << 2);
  int nt = qt / KVB + 1;
  for (int jt = 0; jt < nt; ++jt) {
    int j0 = jt * KVB;
#pragma unroll
    for (int it = 0; it < 2; ++it) {
      int c = tid + (it << 8);
      int row = c >> 3, sl = c & 7;
      s16x8 kv8 = *(const s16x8*)(kb + (hb + j0 + row) * HD + sl * 8);
      *(s16x8*)((char*)kl + row * 128 + ((sl ^ (row & 7)) << 4)) = kv8;
      s16x8 vv8 = *(const s16x8*)(vtb + (((size_t)(b * NH + h)) * HD + row) * TT + j0 + sl * 8);
      *(s16x8*)((char*)vl + row * 128 + ((sl ^ (row & 7)) << 4)) = vv8;
    }
    if (tid < KVB) cgl[tid] = cg[hb + j0 + tid];
    __syncthreads();
    // S = Q K^T (scale pre-folded into q)
    f32x4 s[4];
#pragma unroll
    for (int nf = 0; nf < 4; ++nf) {
      f32x4 z = {0.f, 0.f, 0.f, 0.f};
      int jr = nf * 16 + r16;
      s16x8 kf0 = *(const s16x8*)((char*)kl + jr * 128 + ((q4 ^ (jr & 7)) << 4));
      s16x8 kf1 = *(const s16x8*)((char*)kl + jr * 128 + (((4 | q4) ^ (jr & 7)) << 4));
      z = __builtin_amdgcn_mfma_f32_16x16x32_bf16(qf[0], kf0, z, 0, 0, 0);
      z = __builtin_amdgcn_mfma_f32_16x16x32_bf16(qf[1], kf1, z, 0, 0, 0);
      s[nf] = z;
    }
    // bias + causal mask + online softmax
    float pmax[4] = {-1e30f, -1e30f, -1e30f, -1e30f};
#pragma unroll
    for (int nf = 0; nf < 4; ++nf) {
      int j = j0 + nf * 16 + r16;
      float cgj = cgl[nf * 16 + r16];
#pragma unroll
      for (int r = 0; r < 4; ++r) {
        int i = i_base + r;
        float sv = s[nf][r];
        sv = (j <= i) ? sv - (float)(i - j) * cgj : -1e30f;
        s[nf][r] = sv;
        pmax[r] = fmaxf(pmax[r], sv);
      }
    }
#pragma unroll
    for (int r = 0; r < 4; ++r) pmax[r] = red16_max(pmax[r]);
    float al[4], psum[4];
#pragma unroll
    for (int r = 0; r < 4; ++r) {
      float mn = fmaxf(mr[r], pmax[r]);
      al[r] = __expf(mr[r] - mn);
      mr[r] = mn;
      psum[r] = 0.f;
    }
#pragma unroll
    for (int nf = 0; nf < 4; ++nf) {
#pragma unroll
      for (int r = 0; r < 4; ++r) {
        float p = __expf(s[nf][r] - mr[r]);
        psum[r] += p;
        int il = (q4 << 2) + r;
        int slot = (((nf << 1) | (r16 >> 3)) ^ (il & 7));
        *(unsigned short*)((char*)pl[w] + il * 128 + (slot << 4) + ((r16 & 7) << 1)) = f2b(p);
      }
    }
#pragma unroll
    for (int r = 0; r < 4; ++r) {
      psum[r] = red16_sum(psum[r]);
      lr[r] = lr[r] * al[r] + psum[r];
    }
#pragma unroll
    for (int nf = 0; nf < 4; ++nf) {
      f32x4 a = acc[nf];
      a[0] *= al[0]; a[1] *= al[1]; a[2] *= al[2]; a[3] *= al[3];
      acc[nf] = a;
    }
    __syncthreads();  // P visible (lgkm drained) before PV reads
    // PV: y += P V
    s16x8 pa0 = *(const s16x8*)((char*)pl[w] + r16 * 128 + ((q4 ^ (r16 & 7)) << 4));
    s16x8 pa1 = *(const s16x8*)((char*)pl[w] + r16 * 128 + (((4 | q4) ^ (r16 & 7)) << 4));
#pragma unroll
    for (int nf = 0; nf < 4; ++nf) {
      int dr = nf * 16 + r16;
      s16x8 vf0 = *(const s16x8*)((char*)vl + dr * 128 + ((q4 ^ (dr & 7)) << 4));
      s16x8 vf1 = *(const s16x8*)((char*)vl + dr * 128 + (((4 | q4) ^ (dr & 7)) << 4));
      acc[nf] = __builtin_amdgcn_mfma_f32_16x16x32_bf16(pa0, vf0, acc[nf], 0, 0, 0);
      acc[nf] = __builtin_amdgcn_mfma_f32_16x16x32_bf16(pa1, vf1, acc[nf], 0, 0, 0);
    }
    __syncthreads();  // before next tile overwrites kl/vl
  }
#pragma unroll
  for (int r = 0; r < 4; ++r) {
    float inv = 1.0f / lr[r];
    int i = i_base + r;
#pragma unroll
    for (int nf = 0; nf < 4; ++nf) {
      y[((size_t)(b * TT) + i) * CE + h * HD + nf * 16 + r16] = f2b(acc[nf][r] * inv);
    }
  }
}

extern "C" void kernel_launch(void* const* d_in, const int* in_sizes, int n_in,
                              void* d_out, int out_size, void* d_ws, size_t ws_size,
                              hipStream_t stream) {
  const float* x  = (const float*)d_in[0];
  const float* Wq = (const float*)d_in[1];
  const float* Wk = (const float*)d_in[2];
  const float* Wv = (const float*)d_in[3];
  const float* Wp = (const float*)d_in[4];
  const float* qw = (const float*)d_in[5];
  const float* kw = (const float*)d_in[6];
  const float* om = (const float*)d_in[7];
  const float* u  = (const float*)d_in[8];
  float* out = (float*)d_out;
  char* ws = (char*)d_ws;
  const size_t MB = 1024 * 1024;
  unsigned short* xb  = (unsigned short*)(ws + 0);        // 8MB
  unsigned short* wqt = (unsigned short*)(ws + 8 * MB);   // 2MB each
  unsigned short* wkt = (unsigned short*)(ws + 10 * MB);
  unsigned short* wvt = (unsigned short*)(ws + 12 * MB);
  unsigned short* wpt = (unsigned short*)(ws + 14 * MB);
  float* qf = (float*)(ws + 16 * MB);                     // 16MB each
  float* kf = (float*)(ws + 32 * MB);
  float* vf = (float*)(ws + 48 * MB);
  unsigned short* qbb = (unsigned short*)(ws + 64 * MB);  // 8MB each
  unsigned short* kbb = (unsigned short*)(ws + 72 * MB);
  unsigned short* vtb = (unsigned short*)(ws + 80 * MB);
  float* cg = (float*)(ws + 88 * MB);                     // 256KB
  unsigned short* yb = (unsigned short*)(ws + 16 * MB);   // reuse qf region (dead after rmsgate)

  cvt_x<<<dim3(2048), dim3(256), 0, stream>>>(x, xb, MR * CE / 4);
  cvt_wt<<<dim3(16, 16, 4), dim3(256), 0, stream>>>(Wq, Wk, Wv, Wp, wqt, wkt, wvt, wpt);
  gemm3<<<dim3(8, 32, 3), dim3(256), 0, stream>>>(xb, wqt, wkt, wvt, qf, kf, vf, MR, CE, CE);
  rmsgate<<<dim3(32, 16, 2), dim3(256), 0, stream>>>(qf, kf, vf, qw, kw, om, u, qbb, kbb, vtb, cg);
  attn<<<dim3(32, 16, 2), dim3(256), 0, stream>>>(qbb, kbb, vtb, cg, yb);
  gemm3<<<dim3(8, 32, 1), dim3(256), 0, stream>>>(yb, wpt, wpt, wpt, out, out, out, MR, CE, CE);
}

// Round 3
// 307.316 us; speedup vs baseline: 1.0479x; 1.0479x over previous
//
#include <hip/hip_runtime.h>
#include <hip/hip_bf16.h>

#define NH 16
#define HD 64
#define CE 1024
#define TT 2048
#define BB 2
#define MR (BB*TT)   // 4096 rows
#define SWZ(r) ((((r) & 7)) ^ (((r) >> 3) & 3))

typedef __attribute__((ext_vector_type(4))) float f32x4;
typedef __attribute__((ext_vector_type(16))) float f32x16;
typedef __attribute__((ext_vector_type(8))) short s16x8;
typedef unsigned int u32;
typedef unsigned short u16;

__device__ __forceinline__ void gld16(const void* g, void* l) {
  __builtin_amdgcn_global_load_lds((const __attribute__((address_space(1))) unsigned int*)g,
                                   (__attribute__((address_space(3))) unsigned int*)l, 16, 0, 0);
}
__device__ __forceinline__ u16 f2b(float f) {
  union { __hip_bfloat16 b; u16 u; } t;
  t.b = __float2bfloat16(f);
  return t.u;
}
__device__ __forceinline__ u32 pk2(float a, float b) {
  return (u32)f2b(a) | ((u32)f2b(b) << 16);
}
__device__ __forceinline__ float red64_sum(float v) {
#pragma unroll
  for (int m = 1; m < 64; m <<= 1) v += __shfl_xor(v, m, 64);
  return v;
}
__device__ __forceinline__ float softplusf(float x) {
  return x > 20.0f ? x : log1pf(expf(x));
}

// ---------------- x -> bf16 ----------------
__global__ __launch_bounds__(256) void cvt_x(const float* __restrict__ x,
                                             u16* __restrict__ xb, int n4) {
  int stride = gridDim.x * blockDim.x;
  for (int i = blockIdx.x * blockDim.x + threadIdx.x; i < n4; i += stride) {
    float4 v = ((const float4*)x)[i];
    union { u16 u[4]; uint2 p; } o;
    o.u[0] = f2b(v.x); o.u[1] = f2b(v.y); o.u[2] = f2b(v.z); o.u[3] = f2b(v.w);
    ((uint2*)xb)[i] = o.p;
  }
}

// ------- W [K][N] fp32 -> Wt [N][K] bf16 -------
__global__ __launch_bounds__(256) void cvt_wt(const float* __restrict__ W0, const float* __restrict__ W1,
                                              const float* __restrict__ W2, const float* __restrict__ W3,
                                              u16* __restrict__ T0, u16* __restrict__ T1,
                                              u16* __restrict__ T2, u16* __restrict__ T3) {
  const float* W = blockIdx.z == 0 ? W0 : blockIdx.z == 1 ? W1 : blockIdx.z == 2 ? W2 : W3;
  u16* T = blockIdx.z == 0 ? T0 : blockIdx.z == 1 ? T1 : blockIdx.z == 2 ? T2 : T3;
  __shared__ float t[64][65];
  int k0 = blockIdx.x * 64, n0 = blockIdx.y * 64;
  int row = threadIdx.x >> 2, seg = threadIdx.x & 3;
#pragma unroll
  for (int i = 0; i < 4; ++i) {
    float4 v = *(const float4*)(W + (size_t)(k0 + row) * CE + n0 + seg * 16 + i * 4);
    int c = seg * 16 + i * 4;
    t[row][c + 0] = v.x; t[row][c + 1] = v.y; t[row][c + 2] = v.z; t[row][c + 3] = v.w;
  }
  __syncthreads();
#pragma unroll
  for (int it = 0; it < 2; ++it) {
    int c = threadIdx.x + it * 256;
    int n = c >> 3, ks = (c & 7) * 8;
    union { u16 u[8]; uint4 p; } o;
#pragma unroll
    for (int e = 0; e < 8; ++e) o.u[e] = f2b(t[ks + e][n]);
    *(uint4*)(T + (size_t)(n0 + n) * CE + k0 + ks) = o.p;
  }
}

// ---------------- bf16 GEMM: C[M,N] = A[M,K] @ Bt[N,K]^T ----------------
#define BM 128
#define BN 128
#define BK 64
__global__ __launch_bounds__(256) void gemm3(const u16* __restrict__ A,
    const u16* __restrict__ B0, const u16* __restrict__ B1,
    const u16* __restrict__ B2,
    float* __restrict__ C0, float* __restrict__ C1, float* __restrict__ C2,
    int M, int N, int K) {
  const u16* Bt = blockIdx.z == 0 ? B0 : blockIdx.z == 1 ? B1 : B2;
  float* C = blockIdx.z == 0 ? C0 : blockIdx.z == 1 ? C1 : C2;
  __shared__ __align__(16) u16 aT[BM * BK];  // linear dest; source pre-swizzled
  __shared__ __align__(16) u16 bT[BN * BK];
  int tid = threadIdx.x;
  int w = tid >> 6, lane = tid & 63, q4 = lane >> 4, r16 = lane & 15;
  int m0 = blockIdx.y * BM, n0 = blockIdx.x * BN;
  int wm = (w >> 1) * 64, wn = (w & 1) * 64;
  f32x4 acc[4][4] = {};
  for (int k0 = 0; k0 < K; k0 += BK) {
#pragma unroll
    for (int it = 0; it < 4; ++it) {
      int c = tid + it * 256;
      int row = c >> 3, sl = c & 7;
      gld16(A + (size_t)(m0 + row) * K + k0 + ((sl ^ SWZ(row)) << 3), &aT[c * 8]);
      gld16(Bt + (size_t)(n0 + row) * K + k0 + ((sl ^ SWZ(row)) << 3), &bT[c * 8]);
    }
    __syncthreads();
#pragma unroll
    for (int kk = 0; kk < 2; ++kk) {
      s16x8 af[4], bfr[4];
#pragma unroll
      for (int i = 0; i < 4; ++i) {
        int ra = wm + i * 16 + r16;
        af[i] = *(const s16x8*)((char*)aT + ra * 128 + ((((kk << 2) | q4) ^ SWZ(ra)) << 4));
        int rb = wn + i * 16 + r16;
        bfr[i] = *(const s16x8*)((char*)bT + rb * 128 + ((((kk << 2) | q4) ^ SWZ(rb)) << 4));
      }
#pragma unroll
      for (int i = 0; i < 4; ++i)
#pragma unroll
        for (int j = 0; j < 4; ++j)
          acc[i][j] = __builtin_amdgcn_mfma_f32_16x16x32_bf16(af[i], bfr[j], acc[i][j], 0, 0, 0);
    }
    __syncthreads();
  }
#pragma unroll
  for (int i = 0; i < 4; ++i)
#pragma unroll
    for (int j = 0; j < 4; ++j)
#pragma unroll
      for (int r = 0; r < 4; ++r) {
        int gm = m0 + wm + i * 16 + (q4 << 2) + r;
        int gn = n0 + wn + j * 16 + r16;
        C[(size_t)gm * N + gn] = acc[i][j][r];
      }
}

// ---- RMSNorm(q,k) + gate; q/k -> [B,H,T,D] bf16 (1/8 folded into q), v -> [B,H,D,T] bf16 ----
__global__ __launch_bounds__(256) void rmsgate(const float* __restrict__ q, const float* __restrict__ k,
    const float* __restrict__ v, const float* __restrict__ qw, const float* __restrict__ kw,
    const float* __restrict__ omega, const float* __restrict__ u,
    u16* __restrict__ qb, u16* __restrict__ kb,
    u16* __restrict__ vtb, float* __restrict__ cg) {
  int b = blockIdx.z, h = blockIdx.y, t0 = blockIdx.x * 64;
  int tid = threadIdx.x, w = tid >> 6, lane = tid & 63;
  float uv = u[h * HD + lane];
  float us = red64_sum(uv * uv);
  float un = uv / fmaxf(sqrtf(us), 1e-6f);
  float qwl = qw[lane], kwl = kw[lane];
  float weff = softplusf(omega[h]) * exp2f(-0.5f * (float)(h + 1));
  size_t hb = ((size_t)(b * NH + h)) * TT;
#pragma unroll 4
  for (int it = 0; it < 16; ++it) {
    int t = t0 + w * 16 + it;
    size_t roff = ((size_t)(b * TT + t)) * CE + h * HD + lane;
    float qv = q[roff];
    float rq = rsqrtf(red64_sum(qv * qv) * (1.0f / 64.0f) + 1e-5f);
    qb[(hb + t) * HD + lane] = f2b(qv * rq * qwl * 0.125f);
    float kv = k[roff];
    float rk = rsqrtf(red64_sum(kv * kv) * (1.0f / 64.0f) + 1e-5f);
    float kn = kv * rk * kwl;
    kb[(hb + t) * HD + lane] = f2b(kn);
    float gl = red64_sum(kn * un) * 0.125f;
    if (lane == 0) cg[hb + t] = weff * softplusf(gl);
  }
  __shared__ u16 vt[64 * 65];
  int row = tid >> 2, seg = tid & 3;
#pragma unroll
  for (int i = 0; i < 4; ++i) {
    float4 vv = *(const float4*)(v + ((size_t)(b * TT + t0 + row)) * CE + h * HD + seg * 16 + i * 4);
    int d = seg * 16 + i * 4;
    vt[(d + 0) * 65 + row] = f2b(vv.x);
    vt[(d + 1) * 65 + row] = f2b(vv.y);
    vt[(d + 2) * 65 + row] = f2b(vv.z);
    vt[(d + 3) * 65 + row] = f2b(vv.w);
  }
  __syncthreads();
#pragma unroll
  for (int it = 0; it < 2; ++it) {
    int c = tid + it * 256;
    int d = c >> 3, js = (c & 7) * 8;
    union { u16 u[8]; uint4 p; } o;
#pragma unroll
    for (int e = 0; e < 8; ++e) o.u[e] = vt[d * 65 + js + e];
    *(uint4*)(vtb + (((size_t)(b * NH + h)) * HD + d) * TT + t0 + js) = o.p;
  }
}

// ------------- causal flash attention, swapped-QK^T 32x32 structure -------------
// 4 waves x 32 q-rows (QBLK=128), KVB=64. Lane holds S^T[.][q=lane&31]:
// in-lane softmax, P packed to bf16 in-register (shfl-exchange across halves).
#define KVB 64
__global__ __launch_bounds__(256) void attn(const u16* __restrict__ qb,
    const u16* __restrict__ kb, const u16* __restrict__ vtb,
    const float* __restrict__ cg, u16* __restrict__ y) {
  int b = blockIdx.z, h = blockIdx.y, qb0 = blockIdx.x * 128;
  int tid = threadIdx.x, w = tid >> 6, lane = tid & 63;
  int hi = lane >> 5, q5 = lane & 31;
  __shared__ __align__(16) u16 kl[64 * 64];   // [kv][d]
  __shared__ __align__(16) u16 vl[64 * 64];   // [d][kv]
  __shared__ float cgl[KVB];
  size_t hb = ((size_t)(b * NH + h)) * TT;
  size_t vbase = ((size_t)(b * NH + h)) * HD;
  int qrow = qb0 + w * 32 + q5;
  // Q as B-operand fragments: B[k=d][n=q]: lane needs Q[q5-row][16*kc + 8*hi + e]
  s16x8 qf[4];
#pragma unroll
  for (int kc = 0; kc < 4; ++kc)
    qf[kc] = *(const s16x8*)(qb + (hb + qrow) * HD + kc * 16 + hi * 8);
  f32x16 accO[2] = {};   // O^T tiles (d 0..31 / 32..63) x q
  float m = -1e30f, l = 0.f;
  int qhi = qb0 + w * 32 + 31;
  int nt = (qb0 + 128) / KVB;
  for (int jt = 0; jt < nt; ++jt) {
    int j0 = jt * KVB;
#pragma unroll
    for (int it = 0; it < 2; ++it) {
      int c = tid + (it << 8);
      int row = c >> 3, sl = c & 7;
      gld16(kb + (hb + j0 + row) * HD + ((sl ^ SWZ(row)) << 3), &kl[c * 8]);
      gld16(vtb + (vbase + row) * TT + j0 + ((sl ^ SWZ(row)) << 3), &vl[c * 8]);
    }
    if (tid < KVB) cgl[tid] = cg[hb + j0 + tid];
    __syncthreads();
    if (j0 <= qhi) {
      // S^T = K Q : A = K rows (kv), B = Q cols
      f32x16 s0 = {}, s1 = {};
#pragma unroll
      for (int kc = 0; kc < 4; ++kc) {
        int r0 = q5;
        s16x8 kf0 = *(const s16x8*)((char*)kl + r0 * 128 + ((((kc << 1) | hi) ^ SWZ(r0)) << 4));
        s0 = __builtin_amdgcn_mfma_f32_32x32x16_bf16(kf0, qf[kc], s0, 0, 0, 0);
        int r1 = q5 + 32;
        s16x8 kf1 = *(const s16x8*)((char*)kl + r1 * 128 + ((((kc << 1) | hi) ^ SWZ(r1)) << 4));
        s1 = __builtin_amdgcn_mfma_f32_32x32x16_bf16(kf1, qf[kc], s1, 0, 0, 0);
      }
      // bias + causal mask; in-lane max over 32 + one cross-half exchange
      float pmax = -1e30f;
#pragma unroll
      for (int r = 0; r < 16; ++r) {
        int kvl = (r & 3) + 8 * (r >> 2) + 4 * hi;
        int j = j0 + kvl;
        float sv = s0[r];
        sv = (j <= qrow) ? sv - (float)(qrow - j) * cgl[kvl] : -1e30f;
        s0[r] = sv; pmax = fmaxf(pmax, sv);
        int j2 = j0 + 32 + kvl;
        float sv1 = s1[r];
        sv1 = (j2 <= qrow) ? sv1 - (float)(qrow - j2) * cgl[32 + kvl] : -1e30f;
        s1[r] = sv1; pmax = fmaxf(pmax, sv1);
      }
      pmax = fmaxf(pmax, __shfl_xor(pmax, 32, 64));
      float mn = fmaxf(m, pmax);
      float al = __expf(m - mn);
      m = mn;
      float ps = 0.f;
#pragma unroll
      for (int r = 0; r < 16; ++r) {
        float p0 = __expf(s0[r] - m); s0[r] = p0;
        float p1 = __expf(s1[r] - m); s1[r] = p1;
        ps += p0 + p1;
      }
      ps += __shfl_xor(ps, 32, 64);
      l = l * al + ps;
#pragma unroll
      for (int r = 0; r < 16; ++r) { accO[0][r] *= al; accO[1][r] *= al; }
      // P^T -> bf16 B-frags (half-exchange via shfl_xor 32) + PV: O^T += V^T P^T
      auto pvchunk = [&](f32x16 sc, int cb4) {
        u32 c01 = pk2(sc[0], sc[1]),  c23 = pk2(sc[2], sc[3]);
        u32 c45 = pk2(sc[4], sc[5]),  c67 = pk2(sc[6], sc[7]);
        u32 c89 = pk2(sc[8], sc[9]),  cAB = pk2(sc[10], sc[11]);
        u32 cCD = pk2(sc[12], sc[13]), cEF = pk2(sc[14], sc[15]);
        u32 x01 = (u32)__shfl_xor((int)c01, 32, 64), x23 = (u32)__shfl_xor((int)c23, 32, 64);
        u32 x45 = (u32)__shfl_xor((int)c45, 32, 64), x67 = (u32)__shfl_xor((int)c67, 32, 64);
        u32 x89 = (u32)__shfl_xor((int)c89, 32, 64), xAB = (u32)__shfl_xor((int)cAB, 32, 64);
        u32 xCD = (u32)__shfl_xor((int)cCD, 32, 64), xEF = (u32)__shfl_xor((int)cEF, 32, 64);
        union { u32 wd[4]; s16x8 v; } Bf0, Bf1;
        Bf0.wd[0] = hi ? x45 : c01; Bf0.wd[1] = hi ? x67 : c23;
        Bf0.wd[2] = hi ? c45 : x01; Bf0.wd[3] = hi ? c67 : x23;
        Bf1.wd[0] = hi ? xCD : c89; Bf1.wd[1] = hi ? xEF : cAB;
        Bf1.wd[2] = hi ? cCD : x89; Bf1.wd[3] = hi ? cEF : xAB;
#pragma unroll
        for (int dt = 0; dt < 2; ++dt) {
          int dr = q5 + 32 * dt;
          s16x8 vf0 = *(const s16x8*)((char*)vl + dr * 128 + (((cb4 | hi) ^ SWZ(dr)) << 4));
          s16x8 vf1 = *(const s16x8*)((char*)vl + dr * 128 + ((((cb4 | 2) | hi) ^ SWZ(dr)) << 4));
          accO[dt] = __builtin_amdgcn_mfma_f32_32x32x16_bf16(vf0, Bf0.v, accO[dt], 0, 0, 0);
          accO[dt] = __builtin_amdgcn_mfma_f32_32x32x16_bf16(vf1, Bf1.v, accO[dt], 0, 0, 0);
        }
      };
      pvchunk(s0, 0);
      pvchunk(s1, 4);
    }
    __syncthreads();
  }
  // epilogue: O^T -> per-wave LDS (transpose) -> coalesced bf16 store
  u16* obase = (w < 2) ? (kl + w * 2048) : (vl + (w - 2) * 2048);
  float inv = 1.f / l;
#pragma unroll
  for (int dt = 0; dt < 2; ++dt)
#pragma unroll
    for (int r = 0; r < 16; ++r) {
      int d = 32 * dt + (r & 3) + 8 * (r >> 2) + 4 * hi;
      *(u16*)((char*)obase + q5 * 128 + ((((d >> 3)) ^ SWZ(q5)) << 4) + ((d & 7) << 1)) = f2b(accO[dt][r] * inv);
    }
  __syncthreads();
  int row = lane >> 1, half = lane & 1;
#pragma unroll
  for (int s4 = 0; s4 < 4; ++s4) {
    int slot = half * 4 + s4;
    s16x8 vv = *(const s16x8*)((char*)obase + row * 128 + ((slot ^ SWZ(row)) << 4));
    *(s16x8*)(y + ((size_t)(b * TT) + qb0 + w * 32 + row) * CE + h * HD + half * 32 + s4 * 8) = vv;
  }
}

extern "C" void kernel_launch(void* const* d_in, const int* in_sizes, int n_in,
                              void* d_out, int out_size, void* d_ws, size_t ws_size,
                              hipStream_t stream) {
  const float* x  = (const float*)d_in[0];
  const float* Wq = (const float*)d_in[1];
  const float* Wk = (const float*)d_in[2];
  const float* Wv = (const float*)d_in[3];
  const float* Wp = (const float*)d_in[4];
  const float* qw = (const float*)d_in[5];
  const float* kw = (const float*)d_in[6];
  const float* om = (const float*)d_in[7];
  const float* u  = (const float*)d_in[8];
  float* out = (float*)d_out;
  char* ws = (char*)d_ws;
  const size_t MB = 1024 * 1024;
  u16* xb  = (u16*)(ws + 0);
  u16* wqt = (u16*)(ws + 8 * MB);
  u16* wkt = (u16*)(ws + 10 * MB);
  u16* wvt = (u16*)(ws + 12 * MB);
  u16* wpt = (u16*)(ws + 14 * MB);
  float* qf = (float*)(ws + 16 * MB);
  float* kf = (float*)(ws + 32 * MB);
  float* vf = (float*)(ws + 48 * MB);
  u16* qbb = (u16*)(ws + 64 * MB);
  u16* kbb = (u16*)(ws + 72 * MB);
  u16* vtb = (u16*)(ws + 80 * MB);
  float* cg = (float*)(ws + 88 * MB);
  u16* yb = (u16*)(ws + 16 * MB);   // reuse qf region

  cvt_x<<<dim3(2048), dim3(256), 0, stream>>>(x, xb, MR * CE / 4);
  cvt_wt<<<dim3(16, 16, 4), dim3(256), 0, stream>>>(Wq, Wk, Wv, Wp, wqt, wkt, wvt, wpt);
  gemm3<<<dim3(8, 32, 3), dim3(256), 0, stream>>>(xb, wqt, wkt, wvt, qf, kf, vf, MR, CE, CE);
  rmsgate<<<dim3(32, 16, 2), dim3(256), 0, stream>>>(qf, kf, vf, qw, kw, om, u, qbb, kbb, vtb, cg);
  attn<<<dim3(16, 16, 2), dim3(256), 0, stream>>>(qbb, kbb, vtb, cg, yb);
  gemm3<<<dim3(8, 32, 1), dim3(256), 0, stream>>>(yb, wpt, wpt, wpt, out, out, out, MR, CE, CE);
}